// Round 8
// baseline (128.899 us; speedup 1.0000x reference)
//
#include <hip/hip_runtime.h>

// Medical2DSliceRenderer on MI355X (gfx950) — round 8
//
//   mm = c0 x^2 + c1 xy + c2 y^2 + c3 x + c4 y + c5      (c5 absorbs log2(op*mask))
//   S1[c] = sum_g exp2(mm),  S2[c] = sum_g exp2(mm)^2 * ftop
//   img = sum_c [prod_{c'<c}(1-S1_c')] * S2_c
//
// Round 8:
//  - expanded pixel-basis quadratic: per-row folds T=c1*y+c3, R=(c2*y+c4)*y+c5
//    (5 VALU/row), per-px mm = fma(fma(c0,x,T),x,R) = 2 FMA. 30 VALU + 4 exp2
//    per 4-px iteration (was 38+4) -> predicted 92 busy-cy/iter.
//  - stall decorrelation: the 8 waves of a block share one 4KB segment but
//    START at different 16-gaussian sub-blocks ((w+kk)&7 ring) -> the misses
//    of a segment happen once, in parallel, instead of lockstep-serialized.
//  - plane-major partials part[(chunk,seg)][px]: lane-consecutive 8B stores
//    (WRITE_SIZE 65MB -> 17MB), combine kernel fully coalesced.

#define EPSV 1e-6f
#define NG   4096
#define PP   16384
#define NSL  4
#define GSEG 128         // gaussians per segment
#define SUBB 16          // gaussians per sub-block (8 sub-blocks per segment)

__global__ void prep_kernel(const float* __restrict__ means,
                            const float* __restrict__ scales,
                            const float* __restrict__ rots,
                            const float* __restrict__ ops,
                            const float* __restrict__ fts,
                            float4* __restrict__ gdata) {
    __shared__ float red[256];
    int tid = threadIdx.x;

    float m = -1e30f;
    for (int i = tid; i < NG; i += 256) m = fmaxf(m, scales[i*3+2]);
    red[tid] = m;
    __syncthreads();
    for (int s = 128; s > 0; s >>= 1) {
        if (tid < s) red[tid] = fmaxf(red[tid], red[tid+s]);
        __syncthreads();
    }
    float maxd = 3.0f * red[0];

    int g = blockIdx.x * 256 + tid;
    if (g >= NG) return;

    float qw = rots[g*4+0], qx = rots[g*4+1], qy = rots[g*4+2], qz = rots[g*4+3];
    float inorm = rsqrtf(qw*qw + qx*qx + qy*qy + qz*qz);
    qw *= inorm; qx *= inorm; qy *= inorm; qz *= inorm;

    float s0 = scales[g*3+0], s1 = scales[g*3+1], s2 = scales[g*3+2];

    float r00 = 1.f - 2.f*(qy*qy + qz*qz), r01 = 2.f*(qx*qy - qw*qz), r02 = 2.f*(qx*qz + qw*qy);
    float r10 = 2.f*(qx*qy + qw*qz), r11 = 1.f - 2.f*(qx*qx + qz*qz), r12 = 2.f*(qy*qz - qw*qx);
    float r20 = 2.f*(qx*qz - qw*qy), r21 = 2.f*(qy*qz + qw*qx), r22 = 1.f - 2.f*(qx*qx + qy*qy);

    float a00 = r00*s0, a01 = r01*s1, a02 = r02*s2;
    float a10 = r10*s0, a11 = r11*s1, a12 = r12*s2;
    float a20 = r20*s0, a21 = r21*s1, a22 = r22*s2;

    float c00 = a00*a00 + a01*a01 + a02*a02;
    float c01 = a00*a10 + a01*a11 + a02*a12;
    float c02 = a00*a20 + a01*a21 + a02*a22;
    float c11 = a10*a10 + a11*a11 + a12*a12;
    float c12 = a10*a20 + a11*a21 + a12*a22;
    float c22 = a20*a20 + a21*a21 + a22*a22;

    float izz = 1.0f / (c22 + EPSV);
    float kx = c02 * izz, ky = c12 * izz;
    float sa = c00 - c02*c02*izz + EPSV;
    float sb = c01 - c02*c12*izz;
    float sd = c11 - c12*c12*izz + EPSV;
    float det = sa*sd - sb*sb;
    float idet = 1.0f / det;

    const float C0 = -0.72134752044448170f;   // -0.5 * log2(e)
    float qa = C0 * sd * idet;            // x^2 coeff
    float qb = C0 * (-2.0f * sb * idet);  // xy coeff
    float qd = C0 * sa * idet;            // y^2 coeff

    float mx = means[g*3+0], my = means[g*3+1], mz = means[g*3+2];
    float op = ops[g], ft = fts[g];

    #pragma unroll
    for (int s = 0; s < NSL; ++s) {
        float z = -0.15f + 0.1f * (float)s;
        float zoff = z - mz;
        float m2x = mx + kx * zoff;
        float m2y = my + ky * zoff;
        bool live = (fabsf(mz - z) < maxd) && (op > 1e-12f);
        float lop  = live ? __log2f(op) : -__builtin_inff();
        float ftop = live ? ft / op     : 0.f;
        // expanded coefficients
        float c3 = -(2.0f*qa*m2x + qb*m2y);
        float c4 = -(2.0f*qd*m2y + qb*m2x);
        float c5 = qa*m2x*m2x + qb*m2x*m2y + qd*m2y*m2y + lop;
        float4* o = gdata + ((size_t)(s*NG + g)) * 2;
        o[0] = make_float4(qa, qb, qd, c3);
        o[1] = make_float4(c4, c5, ftop, 0.f);
    }
}

// 1024 blocks x 512 threads (8 waves). block b: cs = b&31 -> (chunk, seg),
// band = b>>5 -> (slice, 16-row band). Wave w: rows {r0, r0+1}, 4 px/lane.
// All 8 waves share the segment (4KB, K$-resident) with rotated sub-block
// start so their misses parallelize instead of lockstep-serializing.
__global__ __launch_bounds__(512, 8)
void render_kernel(const float4* __restrict__ gdata, float2* __restrict__ part) {
    int tid   = threadIdx.x;
    int lane  = tid & 63;
    int w     = __builtin_amdgcn_readfirstlane(tid >> 6);   // 0..7
    int b     = blockIdx.x;
    int cs    = b & 31;          // chunk*8 + seg
    int band  = b >> 5;          // 0..31
    int slice = band >> 3;
    int r0    = (band & 7) * 16 + w * 2;

    const float DL = 2.0f / 127.0f;
    float x0 = -1.0f + (float)lane * DL;
    float x1 = x0 + 64.0f * DL;
    float y0 = -1.0f + (float)r0 * DL;
    float y1 = y0 + DL;

    const float4* base = gdata + ((size_t)slice * NG + cs * GSEG) * 2;

    float a100 = 0.f, a101 = 0.f, a110 = 0.f, a111 = 0.f;   // S1 [row][colhalf]
    float a200 = 0.f, a201 = 0.f, a210 = 0.f, a211 = 0.f;   // S2

    for (int kk = 0; kk < 8; ++kk) {
        int sb = (w + kk) & 7;                    // rotated sub-block
        const float4* q = base + sb * SUBB * 2;   // wave-uniform address
        #pragma unroll 8
        for (int j = 0; j < SUBB; ++j) {
            float4 A = q[2*j+0];   // c0 c1 c2 c3   (s_load, K$-shared)
            float4 B = q[2*j+1];   // c4 c5 ftop pad
            float T0 = fmaf(A.y, y0, A.w);
            float T1 = fmaf(A.y, y1, A.w);
            float R0 = fmaf(fmaf(A.z, y0, B.x), y0, B.y);
            float R1 = fmaf(fmaf(A.z, y1, B.x), y1, B.y);
            float m00 = fmaf(fmaf(A.x, x0, T0), x0, R0);
            float m01 = fmaf(fmaf(A.x, x1, T0), x1, R0);
            float m10 = fmaf(fmaf(A.x, x0, T1), x0, R1);
            float m11 = fmaf(fmaf(A.x, x1, T1), x1, R1);
            float g00 = __builtin_amdgcn_exp2f(m00);
            float g01 = __builtin_amdgcn_exp2f(m01);
            float g10 = __builtin_amdgcn_exp2f(m10);
            float g11 = __builtin_amdgcn_exp2f(m11);
            a100 += g00;  a101 += g01;  a110 += g10;  a111 += g11;
            a200 = fmaf(g00*g00, B.z, a200);
            a201 = fmaf(g01*g01, B.z, a201);
            a210 = fmaf(g10*g10, B.z, a210);
            a211 = fmaf(g11*g11, B.z, a211);
        }
    }

    // plane-major partials: part[cs][slice*PP + row*128 + col] (coalesced)
    size_t o = (size_t)cs * (NSL * PP) + slice * PP + r0 * 128 + lane;
    part[o      ] = make_float2(a100, a200);   // (r0,   lane)
    part[o +  64] = make_float2(a101, a201);   // (r0,   lane+64)
    part[o + 128] = make_float2(a110, a210);   // (r0+1, lane)
    part[o + 192] = make_float2(a111, a211);   // (r0+1, lane+64)
}

// one thread per pixel: sum 8 segments per chunk, then 4-step recursion
__global__ __launch_bounds__(256)
void combine_kernel(const float2* __restrict__ part, float* __restrict__ out) {
    int px = blockIdx.x * 256 + threadIdx.x;
    float img = 0.f, acc = 0.f;
    #pragma unroll
    for (int c = 0; c < 4; ++c) {
        float S1 = 0.f, S2 = 0.f;
        #pragma unroll
        for (int s = 0; s < 8; ++s) {
            float2 v = part[(size_t)(c*8 + s) * (NSL*PP) + px];
            S1 += v.x;  S2 += v.y;
        }
        float om = 1.0f - acc;
        img = fmaf(om, S2, img);
        acc = fmaf(om, S1, acc);
    }
    out[px] = img;
}

extern "C" void kernel_launch(void* const* d_in, const int* in_sizes, int n_in,
                              void* d_out, int out_size, void* d_ws, size_t ws_size,
                              hipStream_t stream) {
    const float* means  = (const float*)d_in[0];
    const float* scales = (const float*)d_in[1];
    const float* rots   = (const float*)d_in[2];
    const float* ops    = (const float*)d_in[3];
    const float* fts    = (const float*)d_in[4];
    float* out = (float*)d_out;

    float4* gdata = (float4*)d_ws;                               // 512 KB
    float2* part  = (float2*)((char*)d_ws + (size_t)NSL*NG*32);  // 16.8 MB

    prep_kernel<<<NG/256, 256, 0, stream>>>(means, scales, rots, ops, fts, gdata);
    render_kernel<<<1024, 512, 0, stream>>>(gdata, part);
    combine_kernel<<<NSL*PP/256, 256, 0, stream>>>(part, out);
}

// Round 9
// 120.977 us; speedup vs baseline: 1.0655x; 1.0655x over previous
//
#include <hip/hip_runtime.h>

// Medical2DSliceRenderer on MI355X (gfx950) — round 9
//
//   mm = c0 x^2 + c1 xy + c2 y^2 + c3 x + c4 y + c5   (c5 absorbs log2(op*mask))
//   S1[c] = sum_g exp2(mm),  S2[c] = sum_g exp2(mm)^2 * ftop
//   img = sum_c [prod_{c'<c}(1-S1_c')] * S2_c
//
// Round 9: lane = one COLUMN, 8 rows per lane. Re-association puts the
// per-gaussian folds in per-lane registers amortized over 8 pixels:
//   A1 = fma(c0,x,c3); A2 = fma(c1,x,c4); A3 = fma(A1,x,c5)   (per g,lane)
//   per row: w = fma(c2,y,A2); m = fma(w,y,A3); g = exp2(m);
//            S1 += g; S2 = fma(g*g, ftop, S2)
// Every per-element fma reads <=1 SGPR -> no v_mov padding (round 8's 117
// vs 84 busy-cy/iter gap). 45 VALU + 8 exp2 per 8 px = 0.30 cy/elem model.
// Feed identical to round 8: block's 8 waves share one 4KB segment
// (K$-resident) with rotated sub-block starts; partials plane-major.

#define EPSV 1e-6f
#define NG   4096
#define PP   16384
#define NSL  4
#define GSEG 128         // gaussians per segment (chunk = 8 segments)
#define SUBB 16          // gaussians per sub-block (8 sub-blocks/segment)

__global__ void prep_kernel(const float* __restrict__ means,
                            const float* __restrict__ scales,
                            const float* __restrict__ rots,
                            const float* __restrict__ ops,
                            const float* __restrict__ fts,
                            float4* __restrict__ gdata) {
    __shared__ float red[256];
    int tid = threadIdx.x;

    float m = -1e30f;
    for (int i = tid; i < NG; i += 256) m = fmaxf(m, scales[i*3+2]);
    red[tid] = m;
    __syncthreads();
    for (int s = 128; s > 0; s >>= 1) {
        if (tid < s) red[tid] = fmaxf(red[tid], red[tid+s]);
        __syncthreads();
    }
    float maxd = 3.0f * red[0];

    int g = blockIdx.x * 256 + tid;
    if (g >= NG) return;

    float qw = rots[g*4+0], qx = rots[g*4+1], qy = rots[g*4+2], qz = rots[g*4+3];
    float inorm = rsqrtf(qw*qw + qx*qx + qy*qy + qz*qz);
    qw *= inorm; qx *= inorm; qy *= inorm; qz *= inorm;

    float s0 = scales[g*3+0], s1 = scales[g*3+1], s2 = scales[g*3+2];

    float r00 = 1.f - 2.f*(qy*qy + qz*qz), r01 = 2.f*(qx*qy - qw*qz), r02 = 2.f*(qx*qz + qw*qy);
    float r10 = 2.f*(qx*qy + qw*qz), r11 = 1.f - 2.f*(qx*qx + qz*qz), r12 = 2.f*(qy*qz - qw*qx);
    float r20 = 2.f*(qx*qz - qw*qy), r21 = 2.f*(qy*qz + qw*qx), r22 = 1.f - 2.f*(qx*qx + qy*qy);

    float a00 = r00*s0, a01 = r01*s1, a02 = r02*s2;
    float a10 = r10*s0, a11 = r11*s1, a12 = r12*s2;
    float a20 = r20*s0, a21 = r21*s1, a22 = r22*s2;

    float c00 = a00*a00 + a01*a01 + a02*a02;
    float c01 = a00*a10 + a01*a11 + a02*a12;
    float c02 = a00*a20 + a01*a21 + a02*a22;
    float c11 = a10*a10 + a11*a11 + a12*a12;
    float c12 = a10*a20 + a11*a21 + a12*a22;
    float c22 = a20*a20 + a21*a21 + a22*a22;

    float izz = 1.0f / (c22 + EPSV);
    float kx = c02 * izz, ky = c12 * izz;
    float sa = c00 - c02*c02*izz + EPSV;
    float sb = c01 - c02*c12*izz;
    float sd = c11 - c12*c12*izz + EPSV;
    float det = sa*sd - sb*sb;
    float idet = 1.0f / det;

    const float C0 = -0.72134752044448170f;   // -0.5 * log2(e)
    float qa = C0 * sd * idet;            // x^2 coeff
    float qb = C0 * (-2.0f * sb * idet);  // xy coeff
    float qd = C0 * sa * idet;            // y^2 coeff

    float mx = means[g*3+0], my = means[g*3+1], mz = means[g*3+2];
    float op = ops[g], ft = fts[g];

    #pragma unroll
    for (int s = 0; s < NSL; ++s) {
        float z = -0.15f + 0.1f * (float)s;
        float zoff = z - mz;
        float m2x = mx + kx * zoff;
        float m2y = my + ky * zoff;
        bool live = (fabsf(mz - z) < maxd) && (op > 1e-12f);
        float lop  = live ? __log2f(op) : -__builtin_inff();
        float ftop = live ? ft / op     : 0.f;
        float c3 = -(2.0f*qa*m2x + qb*m2y);
        float c4 = -(2.0f*qd*m2y + qb*m2x);
        float c5 = qa*m2x*m2x + qb*m2x*m2y + qd*m2y*m2y + lop;
        float4* o = gdata + ((size_t)(s*NG + g)) * 2;
        o[0] = make_float4(qa, qb, qd, c3);    // c0 c1 c2 c3
        o[1] = make_float4(c4, c5, ftop, 0.f);
    }
}

// 512 blocks x 512 threads (8 waves). block b: cs = b&31 (chunk*8+seg),
// band = b>>5 (slice, 32-row group). Wave w: col-half = w&1 (lane = one
// column), rows rbase..rbase+7 where rbase = (band&3)*32 + (w>>1)*8.
// All 8 waves stream the SAME 4KB segment, rotated sub-block starts.
__global__ __launch_bounds__(512, 4)
void render_kernel(const float4* __restrict__ gdata, float2* __restrict__ part) {
    int tid   = threadIdx.x;
    int lane  = tid & 63;
    int w     = __builtin_amdgcn_readfirstlane(tid >> 6);   // 0..7
    int b     = blockIdx.x;
    int cs    = b & 31;          // chunk*8 + seg
    int band  = b >> 5;          // 0..15
    int slice = band >> 2;
    int ch    = w & 1;           // column half
    int rbase = (band & 3) * 32 + (w >> 1) * 8;

    const float DL = 2.0f / 127.0f;
    float x = -1.0f + (float)(ch * 64 + lane) * DL;   // per-lane column

    float yv[8];
    #pragma unroll
    for (int j = 0; j < 8; ++j) yv[j] = -1.0f + (float)(rbase + j) * DL;

    const float4* base = gdata + ((size_t)slice * NG + cs * GSEG) * 2;

    float s1[8], s2[8];
    #pragma unroll
    for (int j = 0; j < 8; ++j) { s1[j] = 0.f; s2[j] = 0.f; }

    for (int kk = 0; kk < 8; ++kk) {
        int sb = (w + kk) & 7;                    // rotated sub-block
        const float4* q = base + sb * SUBB * 2;   // wave-uniform address
        #pragma unroll 8
        for (int t = 0; t < SUBB; ++t) {
            float4 A = q[2*t+0];   // c0 c1 c2 c3   (s_load, K$-shared)
            float4 B = q[2*t+1];   // c4 c5 ftop pad
            float A1 = fmaf(A.x, x, A.w);    // c0*x + c3
            float A2 = fmaf(A.y, x, B.x);    // c1*x + c4
            float A3 = fmaf(A1,  x, B.y);    // A1*x + c5
            #pragma unroll
            for (int j = 0; j < 8; ++j) {
                float wj = fmaf(A.z, yv[j], A2);   // c2*y + A2
                float mj = fmaf(wj, yv[j], A3);
                float gj = __builtin_amdgcn_exp2f(mj);
                s1[j] += gj;
                s2[j] = fmaf(gj * gj, B.z, s2[j]);
            }
        }
    }

    // plane-major partials: part[cs][slice*PP + row*128 + col]  (coalesced)
    size_t ob = (size_t)cs * (NSL * PP) + (size_t)slice * PP
              + (size_t)rbase * 128 + ch * 64 + lane;
    #pragma unroll
    for (int j = 0; j < 8; ++j)
        part[ob + (size_t)j * 128] = make_float2(s1[j], s2[j]);
}

// one thread per pixel: sum 8 segments per chunk, then 4-step recursion
__global__ __launch_bounds__(256)
void combine_kernel(const float2* __restrict__ part, float* __restrict__ out) {
    int px = blockIdx.x * 256 + threadIdx.x;
    float img = 0.f, acc = 0.f;
    #pragma unroll
    for (int c = 0; c < 4; ++c) {
        float S1 = 0.f, S2 = 0.f;
        #pragma unroll
        for (int s = 0; s < 8; ++s) {
            float2 v = part[(size_t)(c*8 + s) * (NSL*PP) + px];
            S1 += v.x;  S2 += v.y;
        }
        float om = 1.0f - acc;
        img = fmaf(om, S2, img);
        acc = fmaf(om, S1, acc);
    }
    out[px] = img;
}

extern "C" void kernel_launch(void* const* d_in, const int* in_sizes, int n_in,
                              void* d_out, int out_size, void* d_ws, size_t ws_size,
                              hipStream_t stream) {
    const float* means  = (const float*)d_in[0];
    const float* scales = (const float*)d_in[1];
    const float* rots   = (const float*)d_in[2];
    const float* ops    = (const float*)d_in[3];
    const float* fts    = (const float*)d_in[4];
    float* out = (float*)d_out;

    float4* gdata = (float4*)d_ws;                               // 512 KB
    float2* part  = (float2*)((char*)d_ws + (size_t)NSL*NG*32);  // 16.8 MB

    prep_kernel<<<NG/256, 256, 0, stream>>>(means, scales, rots, ops, fts, gdata);
    render_kernel<<<512, 512, 0, stream>>>(gdata, part);
    combine_kernel<<<NSL*PP/256, 256, 0, stream>>>(part, out);
}